// Round 7
// baseline (848.748 us; speedup 1.0000x reference)
//
#include <hip/hip_runtime.h>

// ArDCA loss: loss = -sum_{m,i} W[m] * log_softmax(h[i,:] + sum_{j<i} J[i,j,:,X[m,j]])[X[m,i]]
//             + 1e-6 * sum h^2 + 1e-4 * sum_{j<i} J^2
// M=8192, L=256, Q=21. Output: single fp32 scalar.
//
// R7: 4 m's per thread (block = 1024 m's, grid 8 x 256). R4-R6 post-mortems
// showed dur pinned at ~420us across LDS-format/VALU changes; traffic math:
// J triangle (231 MB, L3-resident, >> 4MB/XCD L2) was re-staged per 256-m
// block = 7.4 GB of Infinity-Cache reads = 17.6 TB/s ~ the L3 BW wall.
// 4 m/thread cuts staging+L3 traffic+barriers 4x (-> 1.85 GB); per-item LDS
// gather + VALU unchanged. bf8(e5m2) LDS tiles (R6): unpack = v_perm (f16 =
// bf8<<8, exact), accumulate = v_pk_add_f16, all full-rate. Scale x64 at
// pack, x1/64 in epilogue. Reg terms folded into blockIdx.x==0 staging on
// exact fp32 values. i interleaved across blockIdx.y for load balance.
// dur_us carries ~110us harness constant on top of the pair dispatch.

#define M_SEQ 8192
#define L_POS 256
#define Q_SYM 21
#define QQ    441
#define JC    16
#define NROWS (JC * Q_SYM)       // 336 rows per chunk
#define MPT   4                  // m's per thread

typedef _Float16 half2v __attribute__((ext_vector_type(2)));

__device__ __forceinline__ half2v h2_from_u32(unsigned u) {
    union { unsigned u; half2v h; } c; c.u = u; return c.h;
}

// pack 4 floats to 4 e5m2 bytes
__device__ __forceinline__ unsigned pack4_bf8(float a, float b, float c, float d) {
    int w = __builtin_amdgcn_cvt_pk_bf8_f32(a, b, 0, false);   // bytes 0,1
    w = __builtin_amdgcn_cvt_pk_bf8_f32(c, d, w, true);        // bytes 2,3
    return (unsigned)w;
}

// dword of 4 e5m2 bytes -> two half2 (lo = bytes 0,1 ; hi = bytes 2,3)
// f16 = e5m2_byte << 8  (exact: same exponent bias, subnormals map)
__device__ __forceinline__ half2v bf8lo_h2(unsigned d) {
    return h2_from_u32(__builtin_amdgcn_perm(0u, d, 0x010C000Cu)); // [0,b0,0,b1]
}
__device__ __forceinline__ half2v bf8hi_h2(unsigned d) {
    return h2_from_u32(__builtin_amdgcn_perm(0u, d, 0x030C020Cu)); // [0,b2,0,b3]
}

// gather one row r from the bf8 tile and accumulate 21 values into acc[0..10]
__device__ __forceinline__ void gather_add(const float4* __restrict__ JA,
                                           const float2* __restrict__ JB,
                                           int r, half2v* acc) {
    float4 lo = JA[r];
    float2 hi = JB[r];
    unsigned d0 = __builtin_bit_cast(unsigned, lo.x);
    unsigned d1 = __builtin_bit_cast(unsigned, lo.y);
    unsigned d2 = __builtin_bit_cast(unsigned, lo.z);
    unsigned d3 = __builtin_bit_cast(unsigned, lo.w);
    unsigned d4 = __builtin_bit_cast(unsigned, hi.x);
    unsigned d5 = __builtin_bit_cast(unsigned, hi.y);
    acc[0]  += bf8lo_h2(d0);  acc[1]  += bf8hi_h2(d0);
    acc[2]  += bf8lo_h2(d1);  acc[3]  += bf8hi_h2(d1);
    acc[4]  += bf8lo_h2(d2);  acc[5]  += bf8hi_h2(d2);
    acc[6]  += bf8lo_h2(d3);  acc[7]  += bf8hi_h2(d3);
    acc[8]  += bf8lo_h2(d4);  acc[9]  += bf8hi_h2(d4);
    acc[10] += bf8lo_h2(d5);                       // (v20, 0)
}

// stage one row (jc,b) of the current chunk: 21 strided fp32 -> bf8*21 in LDS;
// optionally accumulate sum(J^2) on the exact fp32 values.
__device__ __forceinline__ void stage_row(const float* __restrict__ Jsrc,
                                          float4* __restrict__ JA,
                                          float2* __restrict__ JB,
                                          int row, int jc, int b,
                                          bool reg_on, float* regsum) {
    const float SC = 64.0f;
    const float* s = Jsrc + jc * QQ + b;
    float v[Q_SYM];
    #pragma unroll
    for (int a = 0; a < Q_SYM; ++a) v[a] = s[a * Q_SYM];
    if (reg_on) {
        float rs = 0.0f;
        #pragma unroll
        for (int a = 0; a < Q_SYM; ++a) rs += v[a] * v[a];
        *regsum += rs;
    }
    unsigned w0 = pack4_bf8(SC*v[0],  SC*v[1],  SC*v[2],  SC*v[3]);
    unsigned w1 = pack4_bf8(SC*v[4],  SC*v[5],  SC*v[6],  SC*v[7]);
    unsigned w2 = pack4_bf8(SC*v[8],  SC*v[9],  SC*v[10], SC*v[11]);
    unsigned w3 = pack4_bf8(SC*v[12], SC*v[13], SC*v[14], SC*v[15]);
    unsigned w4 = pack4_bf8(SC*v[16], SC*v[17], SC*v[18], SC*v[19]);
    unsigned w5 = (unsigned)__builtin_amdgcn_cvt_pk_bf8_f32(SC*v[20], 0.f, 0, false);
    JA[row] = make_float4(__builtin_bit_cast(float, w0),
                          __builtin_bit_cast(float, w1),
                          __builtin_bit_cast(float, w2),
                          __builtin_bit_cast(float, w3));
    JB[row] = make_float2(__builtin_bit_cast(float, w4),
                          __builtin_bit_cast(float, w5));
}

__device__ __forceinline__ float nll_one(const float* hrow, const half2v* acc,
                                         int g, float w) {
    const float INV = 1.0f / 64.0f;
    float logits[Q_SYM];
    #pragma unroll
    for (int k = 0; k < 10; ++k) {
        logits[2 * k]     = hrow[2 * k]     + (float)acc[k].x * INV;
        logits[2 * k + 1] = hrow[2 * k + 1] + (float)acc[k].y * INV;
    }
    logits[20] = hrow[20] + (float)acc[10].x * INV;

    float mx = -3.4e38f;
    #pragma unroll
    for (int a = 0; a < Q_SYM; ++a) mx = fmaxf(mx, logits[a]);
    float s = 0.0f;
    #pragma unroll
    for (int a = 0; a < Q_SYM; ++a) s += __expf(logits[a] - mx);
    float gold = 0.0f;
    #pragma unroll
    for (int a = 0; a < Q_SYM; ++a) gold = (a == g) ? logits[a] : gold;
    float logp = gold - mx - __logf(s);
    return -w * logp;
}

__device__ __forceinline__ float wave_block_reduce(float v, float* red, int tid) {
    #pragma unroll
    for (int off = 32; off > 0; off >>= 1) v += __shfl_down(v, off, 64);
    if ((tid & 63) == 0) red[tid >> 6] = v;
    __syncthreads();
    return red[0] + red[1] + red[2] + red[3];
}

__global__ void zero_out(float* __restrict__ out) { out[0] = 0.0f; }

// One block per (m-chunk of 1024, i). Each thread owns 4 m's.
__global__ __launch_bounds__(256) void pair_nll_kernel(const int* __restrict__ X,
                                                       const float* __restrict__ W,
                                                       const float* __restrict__ h,
                                                       const float* __restrict__ J,
                                                       float* __restrict__ out) {
    __shared__ float4 JA[NROWS];     // 16 bf8 per row (values 0..15)  5376 B
    __shared__ float2 JB[NROWS];     // 5 bf8 + pad    (values 16..20) 2688 B
    __shared__ float red[4];

    const int tid = threadIdx.x;
    // interleave i across dispatch order for load balance (work ~ i)
    const int i  = ((blockIdx.y & 1) << 7) | (blockIdx.y >> 1);
    const int m0 = blockIdx.x * (256 * MPT) + tid;
    const bool do_reg = (blockIdx.x == 0);
    const int* xrow0 = X + (size_t)m0 * L_POS;
    const int* xrow1 = xrow0 + 256 * L_POS;
    const int* xrow2 = xrow0 + 512 * L_POS;
    const int* xrow3 = xrow0 + 768 * L_POS;

    // thread-owned staging rows (fixed for whole kernel)
    const int row0 = tid;                       // 0..255
    const int jc0  = row0 / Q_SYM;
    const int b0   = row0 - jc0 * Q_SYM;
    const int row1 = tid + 256;                 // 256..335 valid when tid < 80
    const int jc1  = row1 / Q_SYM;
    const int b1   = row1 - jc1 * Q_SYM;
    const bool has_row1 = (row1 < NROWS);

    half2v acc[MPT][11];   // per m: 10 pairs + [10].x for value 20
    #pragma unroll
    for (int p = 0; p < MPT; ++p)
        #pragma unroll
        for (int k = 0; k < 11; ++k) { acc[p][k].x = (_Float16)0.f; acc[p][k].y = (_Float16)0.f; }
    float regsum = 0.0f;

    for (int j0 = 0; j0 < i; j0 += JC) {
        const float* Jsrc = J + ((size_t)i * L_POS + j0) * QQ;
        __syncthreads();   // protect previous chunk's LDS reads

        stage_row(Jsrc, JA, JB, row0, jc0, b0, do_reg && (j0 + jc0 < i), &regsum);
        if (has_row1)
            stage_row(Jsrc, JA, JB, row1, jc1, b1, do_reg && (j0 + jc1 < i), &regsum);
        __syncthreads();

        // process jc in groups of 4 to bound live X registers
        #pragma unroll
        for (int g4 = 0; g4 < 4; ++g4) {
            int4 x0 = *(const int4*)(xrow0 + j0 + 4 * g4);
            int4 x1 = *(const int4*)(xrow1 + j0 + 4 * g4);
            int4 x2 = *(const int4*)(xrow2 + j0 + 4 * g4);
            int4 x3 = *(const int4*)(xrow3 + j0 + 4 * g4);
            int v0[4] = {x0.x, x0.y, x0.z, x0.w};
            int v1[4] = {x1.x, x1.y, x1.z, x1.w};
            int v2[4] = {x2.x, x2.y, x2.z, x2.w};
            int v3[4] = {x3.x, x3.y, x3.z, x3.w};
            #pragma unroll
            for (int t = 0; t < 4; ++t) {
                int jc = g4 * 4 + t;
                if (j0 + jc < i) {   // block-uniform guard (scalar branch)
                    int rbase = jc * Q_SYM;
                    gather_add(JA, JB, rbase + v0[t], acc[0]);
                    gather_add(JA, JB, rbase + v1[t], acc[1]);
                    gather_add(JA, JB, rbase + v2[t], acc[2]);
                    gather_add(JA, JB, rbase + v3[t], acc[3]);
                }
            }
        }
    }

    // ---- epilogue: 4 NLL terms + reg fold
    const float* hrow = h + i * Q_SYM;
    float v = 0.0f;
    v += nll_one(hrow, acc[0], xrow0[i], W[m0]);
    v += nll_one(hrow, acc[1], xrow1[i], W[m0 + 256]);
    v += nll_one(hrow, acc[2], xrow2[i], W[m0 + 512]);
    v += nll_one(hrow, acc[3], xrow3[i], W[m0 + 768]);

    if (do_reg) {
        v += 1e-4f * regsum;
        if (tid < Q_SYM) {
            float hv = hrow[tid];
            v += 1e-6f * hv * hv;
        }
    }

    __syncthreads();   // LDS reuse safety before reduction
    float tot = wave_block_reduce(v, red, tid);
    if (tid == 0) atomicAdd(out, tot);
}

extern "C" void kernel_launch(void* const* d_in, const int* in_sizes, int n_in,
                              void* d_out, int out_size, void* d_ws, size_t ws_size,
                              hipStream_t stream) {
    const int*   X = (const int*)d_in[0];
    const float* W = (const float*)d_in[1];
    const float* h = (const float*)d_in[2];
    const float* J = (const float*)d_in[3];
    float* out = (float*)d_out;

    hipLaunchKernelGGL(zero_out, dim3(1), dim3(1), 0, stream, out);
    dim3 grid(M_SEQ / (256 * MPT), L_POS);
    hipLaunchKernelGGL(pair_nll_kernel, grid, dim3(256), 0, stream, X, W, h, J, out);
}